// Round 4
// baseline (960.708 us; speedup 1.0000x reference)
//
#include <hip/hip_runtime.h>
#include <hip/hip_bf16.h>

// Problem: B=16,S=64 -> BS=1024 sequences, L=128 tokens, D=512, F=256 filters
// per conv width Kw in {3,4,5}, V=30000.
// out[bs, c*256 + f] = relu(max_t (conv_c(x)[t,f]) + b_c[f]), fp32.
//
// R2: XOR-swizzled LDS -> bank conflicts 1.5e8 -> 0 (550->461 us).
// R3: XCD-aware grid -> FETCH 1.65 GB -> 0.70 GB, but dur 461->446: the
//     m97 2-barrier K-loop structure is the binding constraint, not HBM.
// R4: RESTRUCTURE. One block per (bs, conv): the whole x-slab (132x512 bf16
//     = 135 KB) is staged into LDS ONCE, then the K-loop has NO barriers:
//     A-frags ds_read from the persistent swizzled slab, B-frags stream
//     global(L2)->registers with depth-2 double-buffering. 512 threads,
//     2x4 wave grid, wave tile 64x64 (4x4 of 16x16x32 bf16 MFMA).

typedef __bf16 bf16x8 __attribute__((ext_vector_type(8)));
typedef float f32x4 __attribute__((ext_vector_type(4)));

#define XROWS 132                   // 128 real + 4 zero pad (K=5 window)
#define XELEMS ((size_t)1024 * XROWS * 512)
#define WQ_ELEMS 1572864            // 256*(1536+2048+2560)
#define SLAB_BYTES (XROWS * 512 * 2)  // 135168 B

__device__ __forceinline__ void async16(const void* g, void* l) {
    __builtin_amdgcn_global_load_lds(
        (const __attribute__((address_space(1))) void*)g,
        (__attribute__((address_space(3))) void*)l, 16, 0, 0);
}

// ---------------- pack_x: x[bs][t][d] = bf16(embed[text[bs,t], d]) ----------
__global__ void pack_x_kernel(const int* __restrict__ text,
                              const float* __restrict__ embed,
                              __bf16* __restrict__ x) {
    const int tid  = threadIdx.x;
    const int rr   = blockIdx.x * 4 + (tid >> 6);   // global row 0..135167
    const int lane = tid & 63;
    const int bs   = rr / XROWS;
    const int t    = rr - bs * XROWS;
    __bf16* dst = x + (size_t)rr * 512 + lane * 8;
    bf16x8 o = {};
    if (t < 128) {
        const int token = text[bs * 128 + t];
        const float* src = embed + (size_t)token * 512 + lane * 8;
        const float4 v0 = *(const float4*)(src);
        const float4 v1 = *(const float4*)(src + 4);
        o[0] = (__bf16)v0.x; o[1] = (__bf16)v0.y;
        o[2] = (__bf16)v0.z; o[3] = (__bf16)v0.w;
        o[4] = (__bf16)v1.x; o[5] = (__bf16)v1.y;
        o[6] = (__bf16)v1.z; o[7] = (__bf16)v1.w;
    }
    *(bf16x8*)dst = o;
}

// ---------------- pack_w: wq[c][f][k][d] = bf16(w_c[f][d][k]) ---------------
__global__ void pack_w_kernel(const float* __restrict__ w3,
                              const float* __restrict__ w4,
                              const float* __restrict__ w5,
                              __bf16* __restrict__ wq) {
    const int e = blockIdx.x * 256 + threadIdx.x;   // 0..1572863
    int rel, Kw; const float* w;
    if (e < 393216)      { rel = e;          Kw = 3; w = w3; }
    else if (e < 917504) { rel = e - 393216; Kw = 4; w = w4; }
    else                 { rel = e - 917504; Kw = 5; w = w5; }
    const int fk = rel >> 9;          // f*Kw + k
    const int d  = rel & 511;
    const int f  = fk / Kw;
    const int k  = fk - f * Kw;
    wq[e] = (__bf16)w[((size_t)f * 512 + d) * Kw + k];
}

// ---------------- slab-resident conv GEMM + max + bias + relu ---------------
// Grid 3072 = (bs, conv). XCD decode: xcd=lin&7, idx=lin>>3, bs=(idx/3)*8+xcd,
// c=idx%3 -> the 3 blocks of one bs are consecutive on one XCD (slab + 3 MB
// weights stay L2-hot).
// LDS slab swizzle: 16B block bb of row r holds data block bb^(r&7).
// K index q = tap*512 + d; kq steps K=32 (one MFMA), 16 kq per tap.
__global__ __launch_bounds__(512) void conv_gemm_kernel(
        const __bf16* __restrict__ x,
        const __bf16* __restrict__ wq,
        const float* __restrict__ b3,
        const float* __restrict__ b4,
        const float* __restrict__ b5,
        float* __restrict__ out) {
    extern __shared__ __bf16 slab[];   // 132*512 bf16 = 135168 B

    const int tid  = threadIdx.x;
    const int wave = tid >> 6;
    const int lane = tid & 63;

    const int lin = blockIdx.x;
    const int xcd = lin & 7;
    const int idx = lin >> 3;             // 0..383
    const int bsh = idx / 3;
    const int c   = idx - bsh * 3;        // conv 0..2 (Kw = 3+c)
    const int bs  = bsh * 8 + xcd;        // 0..1023
    const int Kd  = (3 + c) << 9;         // 1536 / 2048 / 2560
    const int nkq = Kd >> 5;              // 48 / 64 / 80 (even)
    const int wbase = (c == 0) ? 0 : (c == 1) ? 393216 : 917504;

    const __bf16* xb = x + (size_t)bs * (XROWS * 512);
    const __bf16* wb = wq + wbase;

    // ---- stage slab once: one async16 = one full row (64 lanes x 16 B) ----
    for (int r = wave; r < XROWS; r += 8) {
        const __bf16* src = xb + r * 512 + ((lane ^ (r & 7)) << 3);
        async16(src, &slab[r * 512]);
    }
    __syncthreads();   // drains vmcnt; slab valid for the whole K loop

    // ---- wave grid 2(m) x 4(n); wave tile M=64, N=64 ----
    const int wm = wave & 1, wn = wave >> 1;
    const int lm = lane & 15, lk = lane >> 4;

    const __bf16* bp[4];
#pragma unroll
    for (int nt = 0; nt < 4; ++nt)
        bp[nt] = wb + (size_t)(wn * 64 + nt * 16 + lm) * Kd + lk * 8;

    f32x4 acc[4][4];
#pragma unroll
    for (int i = 0; i < 4; ++i)
#pragma unroll
        for (int j = 0; j < 4; ++j) acc[i][j] = (f32x4){0.f, 0.f, 0.f, 0.f};

    auto loadB = [&](bf16x8* d, int kq) {
#pragma unroll
        for (int nt = 0; nt < 4; ++nt)
            d[nt] = *(const bf16x8*)(bp[nt] + kq * 32);
    };
    auto loadA = [&](bf16x8* d, int kq) {
        const int tap  = kq >> 4;
        const int brow = wm * 64 + lm + tap;            // slab row (t + tap)
        const int bblk = ((kq & 15) << 2) | lk;         // logical 16B block
        const __bf16* ab = &slab[brow * 512 + ((bblk ^ (brow & 7)) << 3)];
#pragma unroll
        for (int mt = 0; mt < 4; ++mt)
            d[mt] = *(const bf16x8*)(ab + mt * 16 * 512);
    };
    auto mfma16 = [&](const bf16x8* a, const bf16x8* b) {
#pragma unroll
        for (int mt = 0; mt < 4; ++mt)
#pragma unroll
            for (int nt = 0; nt < 4; ++nt)
                acc[mt][nt] = __builtin_amdgcn_mfma_f32_16x16x32_bf16(
                    a[mt], b[nt], acc[mt][nt], 0, 0, 0);
    };

    // ---- barrier-free K loop, depth-2 register double buffer ----
    bf16x8 a0[4], a1[4], b0[4], b1[4];
    loadA(a0, 0); loadB(b0, 0);
    loadA(a1, 1); loadB(b1, 1);
    for (int kq = 0; kq < nkq; kq += 2) {
        mfma16(a0, b0);
        {
            const int k2 = (kq + 2 < nkq) ? kq + 2 : kq;  // clamp: harmless
            loadA(a0, k2); loadB(b0, k2);
        }
        mfma16(a1, b1);
        {
            const int k3 = (kq + 3 < nkq) ? kq + 3 : kq;
            loadA(a1, k3); loadB(b1, k3);
        }
    }

    // ---- epilogue: max over valid t, cross-lane, cross-wave, bias+relu ----
    const int Tv = 126 - c;               // 126/125/124 valid positions
    float cmax[4];
#pragma unroll
    for (int nt = 0; nt < 4; ++nt) {
        float mx = -3.0e38f;
#pragma unroll
        for (int mt = 0; mt < 4; ++mt) {
            const int mb = wm * 64 + mt * 16 + lk * 4;
#pragma unroll
            for (int r = 0; r < 4; ++r) {
                const float v = acc[mt][nt][r];
                if (mb + r < Tv) mx = fmaxf(mx, v);
            }
        }
        mx = fmaxf(mx, __shfl_xor(mx, 16, 64));
        mx = fmaxf(mx, __shfl_xor(mx, 32, 64));
        cmax[nt] = mx;
    }
    __syncthreads();                      // all slab reads done; reuse as red
    float* red = (float*)slab;            // [2][256]
    if (lk == 0) {
#pragma unroll
        for (int nt = 0; nt < 4; ++nt)
            red[wm * 256 + wn * 64 + nt * 16 + lm] = cmax[nt];
    }
    __syncthreads();
    if (tid < 256) {
        const float* bias = (c == 0) ? b3 : (c == 1) ? b4 : b5;
        float v = fmaxf(red[tid], red[256 + tid]) + bias[tid];
        out[(size_t)bs * 768 + c * 256 + tid] = fmaxf(v, 0.f);
    }
}

extern "C" void kernel_launch(void* const* d_in, const int* in_sizes, int n_in,
                              void* d_out, int out_size, void* d_ws, size_t ws_size,
                              hipStream_t stream) {
    const int*   text  = (const int*)d_in[0];
    const float* embed = (const float*)d_in[1];
    const float* w3    = (const float*)d_in[2];
    const float* b3    = (const float*)d_in[3];
    const float* w4    = (const float*)d_in[4];
    const float* b4    = (const float*)d_in[5];
    const float* w5    = (const float*)d_in[6];
    const float* b5    = (const float*)d_in[7];
    float* out = (float*)d_out;

    __bf16* x  = (__bf16*)d_ws;                 // 1024*132*512 bf16 = 138.4 MB
    __bf16* wq = x + XELEMS;                    // 1572864 bf16 = 3.1 MB

    // Allow >64 KB dynamic LDS (metadata call, not stream-ordered; safe
    // under graph capture, idempotent per call).
    (void)hipFuncSetAttribute((const void*)conv_gemm_kernel,
                              hipFuncAttributeMaxDynamicSharedMemorySize,
                              SLAB_BYTES);

    pack_x_kernel<<<1024 * XROWS / 4, 256, 0, stream>>>(text, embed, x);
    pack_w_kernel<<<WQ_ELEMS / 256, 256, 0, stream>>>(w3, w4, w5, wq);
    conv_gemm_kernel<<<3072, 512, SLAB_BYTES, stream>>>(x, wq, b3, b4, b5, out);
}

// Round 5
// 506.772 us; speedup vs baseline: 1.8957x; 1.8957x over previous
//
#include <hip/hip_runtime.h>
#include <hip/hip_bf16.h>

// Problem: B=16,S=64 -> BS=1024 sequences, L=128 tokens, D=512, F=256 filters
// per conv width Kw in {3,4,5}, V=30000.
// out[bs, c*256 + f] = relu(max_t (conv_c(x)[t,f]) + b_c[f]), fp32.
//
// R2: XOR-swizzle LDS -> conflicts 1.5e8 -> 0 (550->461 us).
// R3: XCD grid remap -> FETCH 1.65->0.70 GB, dur 446: structure-bound.
// R4: slab-resident barrier-free FAILED (877 us): B loads were 3-5 KB-strided
//     per-lane scatters -> ~128 KB of L2 lines per kq, 4x over MFMA time.
// R5: same slab structure, B fixed: pack_w emits MFMA-fragment-ordered 1 KB
//     chunks so every B-frag is ONE contiguous global_load_dwordx4 (imm
//     offsets, wave-uniform base). B prefetch depth 4, A (LDS slab, padded
//     stride 520) depth 2, unrolled 16-kq tap body, zero barriers in K-loop.

typedef __bf16 bf16x8 __attribute__((ext_vector_type(8)));
typedef float f32x4 __attribute__((ext_vector_type(4)));

#define XROWS 132                     // 128 real + 4 zero pad (K=5 window)
#define XELEMS ((size_t)1024 * XROWS * 512)
#define SLAB_STRIDE 520               // 512 + 8 bf16 pad (bank spread)
#define SLAB_ROWS 133                 // 132 staged + 1 prefetch-overrun row
#define SLAB_BYTES (SLAB_ROWS * SLAB_STRIDE * 2)   // 138320 B
#define WQ_ELEMS 1572864              // 3072 chunks * 512 elem

__device__ __forceinline__ void async16(const void* g, void* l) {
    __builtin_amdgcn_global_load_lds(
        (const __attribute__((address_space(1))) void*)g,
        (__attribute__((address_space(3))) void*)l, 16, 0, 0);
}

// ---------------- pack_x: x[bs][t][d] = bf16(embed[text[bs,t], d]) ----------
__global__ void pack_x_kernel(const int* __restrict__ text,
                              const float* __restrict__ embed,
                              __bf16* __restrict__ x) {
    const int tid  = threadIdx.x;
    const int rr   = blockIdx.x * 4 + (tid >> 6);   // global row 0..135167
    const int lane = tid & 63;
    const int bs   = rr / XROWS;
    const int t    = rr - bs * XROWS;
    __bf16* dst = x + (size_t)rr * 512 + lane * 8;
    bf16x8 o = {};
    if (t < 128) {
        const int token = text[bs * 128 + t];
        const float* src = embed + (size_t)token * 512 + lane * 8;
        const float4 v0 = *(const float4*)(src);
        const float4 v1 = *(const float4*)(src + 4);
        o[0] = (__bf16)v0.x; o[1] = (__bf16)v0.y;
        o[2] = (__bf16)v0.z; o[3] = (__bf16)v0.w;
        o[4] = (__bf16)v1.x; o[5] = (__bf16)v1.y;
        o[6] = (__bf16)v1.z; o[7] = (__bf16)v1.w;
    }
    *(bf16x8*)dst = o;
}

// -------- pack_w: MFMA-fragment-ordered chunks -------------------------------
// Chunk g = (c, kq, n16), 1024 B = 64 lanes x 16 B. Element (lane, j):
//   f = n16*16 + (lane&15), k = kq*32 + (lane>>4)*8 + j, tap = k>>9, d = k&511
//   src = w_c[f][d][tap]  (layout [F][D][Kw]).
// Chunk bases (chunks): c0 = 0, c1 = 768, c2 = 1792; total 3072.
__global__ void pack_w_kernel(const float* __restrict__ w3,
                              const float* __restrict__ w4,
                              const float* __restrict__ w5,
                              __bf16* __restrict__ wq) {
    const int t    = blockIdx.x * 256 + threadIdx.x;  // 0..196607
    const int g    = t >> 6;                          // chunk 0..3071
    const int lane = t & 63;
    int rel, Kw; const float* w;
    if (g < 768)       { rel = g;        Kw = 3; w = w3; }
    else if (g < 1792) { rel = g - 768;  Kw = 4; w = w4; }
    else               { rel = g - 1792; Kw = 5; w = w5; }
    const int kq  = rel >> 4;
    const int n16 = rel & 15;
    const int f   = n16 * 16 + (lane & 15);
    const int k0  = kq * 32 + (lane >> 4) * 8;        // frag never straddles tap
    const int tap = k0 >> 9;
    const int d0  = k0 & 511;
    const float* src = w + ((size_t)f * 512 + d0) * Kw + tap;
    bf16x8 o;
#pragma unroll
    for (int j = 0; j < 8; ++j) o[j] = (__bf16)src[j * Kw];
    *(bf16x8*)(wq + (size_t)t * 8) = o;
}

// ---------------- slab-resident conv GEMM + max + bias + relu ---------------
// Grid 3072 = (bs, conv), XCD decode. 512 thr = 8 waves, grid 2m x 4n, wave
// tile 64x64 (4x4 of 16x16x32 bf16). A: persistent LDS slab (133x520 bf16),
// B: fragment-ordered global chunks, depth-4 register prefetch. No barriers
// in the K-loop.
__global__ __launch_bounds__(512, 2) void conv_gemm_kernel(
        const __bf16* __restrict__ x,
        const __bf16* __restrict__ wq,
        const float* __restrict__ b3,
        const float* __restrict__ b4,
        const float* __restrict__ b5,
        float* __restrict__ out) {
    extern __shared__ __bf16 slab[];   // SLAB_ROWS x SLAB_STRIDE

    const int tid  = threadIdx.x;
    const int wave = tid >> 6;
    const int lane = tid & 63;

    const int lin = blockIdx.x;
    const int xcd = lin & 7;
    const int idx = lin >> 3;             // 0..383
    const int bsh = idx / 3;
    const int c   = idx - bsh * 3;        // conv 0..2 (Kw = 3+c)
    const int bs  = bsh * 8 + xcd;        // 0..1023
    const int KW  = 3 + c;
    const int nkq = KW << 4;              // 48 / 64 / 80
    const int cbase = (c == 0) ? 0 : (c == 1) ? 393216 : 917504;  // elems

    const __bf16* xb = x + (size_t)bs * (XROWS * 512);

    // ---- stage slab once (rows 0..131; row 132 is prefetch-slack) ----
    for (int r = wave; r < XROWS; r += 8)
        async16(xb + r * 512 + lane * 8, &slab[r * SLAB_STRIDE]);
    __syncthreads();

    // ---- wave grid 2(m) x 4(n); wave tile 64x64 ----
    const int wm = wave & 1, wn = wave >> 1;
    const int lm = lane & 15, lk = lane >> 4;

    // A base: row (wm*64 + lm + tap), col lk*8; per-tap advance += 520.
    const __bf16* ap = slab + (wm * 64 + lm) * SLAB_STRIDE + lk * 8;
    // B base: wave-uniform chunk group + lane offset.
    const __bf16* bp = wq + cbase + (size_t)(wn * 4) * 512 + lane * 8;

    f32x4 acc[4][4];
#pragma unroll
    for (int i = 0; i < 4; ++i)
#pragma unroll
        for (int j = 0; j < 4; ++j) acc[i][j] = (f32x4){0.f, 0.f, 0.f, 0.f};

    bf16x8 A2[2][4], B4[4][4];

    auto loadB = [&](bf16x8* d, int kb) {
        const __bf16* p = bp + (size_t)kb * 8192;
        d[0] = *(const bf16x8*)(p);
        d[1] = *(const bf16x8*)(p + 512);
        d[2] = *(const bf16x8*)(p + 1024);
        d[3] = *(const bf16x8*)(p + 1536);
    };
    auto mfma16 = [&](const bf16x8* a, const bf16x8* b) {
#pragma unroll
        for (int mt = 0; mt < 4; ++mt)
#pragma unroll
            for (int nt = 0; nt < 4; ++nt)
                acc[mt][nt] = __builtin_amdgcn_mfma_f32_16x16x32_bf16(
                    a[mt], b[nt], acc[mt][nt], 0, 0, 0);
    };

    // ---- prolog: B for kq 0..3, A for kq 0..1 (all < nkq >= 48) ----
    loadB(B4[0], 0); loadB(B4[1], 1); loadB(B4[2], 2); loadB(B4[3], 3);
#pragma unroll
    for (int mt = 0; mt < 4; ++mt) {
        A2[0][mt] = *(const bf16x8*)(ap + mt * (16 * SLAB_STRIDE));
        A2[1][mt] = *(const bf16x8*)(ap + 32 + mt * (16 * SLAB_STRIDE));
    }

    // ---- barrier-free K loop: taps outer, 16 kq unrolled per tap ----
    for (int tap = 0; tap < KW; ++tap) {
        const int kq0 = tap << 4;
#pragma unroll
        for (int q = 0; q < 16; ++q) {
            mfma16(A2[q & 1], B4[q & 3]);
            // prefetch A for kq+2 (crosses into tap+1 for q=14,15 via +520)
            {
                const int off = (q + 2 < 16) ? (q + 2) * 32
                                             : SLAB_STRIDE + (q - 14) * 32;
#pragma unroll
                for (int mt = 0; mt < 4; ++mt)
                    A2[q & 1][mt] = *(const bf16x8*)
                        (ap + off + mt * (16 * SLAB_STRIDE));
            }
            // prefetch B for kq+4 (uniform clamp; clamped slots never used)
            {
                int kb = kq0 + q + 4;
                kb = (kb < nkq) ? kb : (nkq - 1);
                loadB(B4[q & 3], kb);
            }
        }
        ap += SLAB_STRIDE;
    }

    // ---- epilogue: max over valid t, cross-lane, cross-wave, bias+relu ----
    const int Tv = 126 - c;               // 126/125/124 valid positions
    float cmax[4];
#pragma unroll
    for (int nt = 0; nt < 4; ++nt) {
        float mx = -3.0e38f;
#pragma unroll
        for (int mt = 0; mt < 4; ++mt) {
            const int mb = wm * 64 + mt * 16 + lk * 4;
#pragma unroll
            for (int r = 0; r < 4; ++r) {
                const float v = acc[mt][nt][r];
                if (mb + r < Tv) mx = fmaxf(mx, v);
            }
        }
        mx = fmaxf(mx, __shfl_xor(mx, 16, 64));
        mx = fmaxf(mx, __shfl_xor(mx, 32, 64));
        cmax[nt] = mx;
    }
    __syncthreads();                      // all slab reads done; reuse as red
    float* red = (float*)slab;            // [2][256]
    if (lk == 0) {
#pragma unroll
        for (int nt = 0; nt < 4; ++nt)
            red[wm * 256 + wn * 64 + nt * 16 + lm] = cmax[nt];
    }
    __syncthreads();
    if (tid < 256) {
        const float* bias = (c == 0) ? b3 : (c == 1) ? b4 : b5;
        float v = fmaxf(red[tid], red[256 + tid]) + bias[tid];
        out[(size_t)bs * 768 + c * 256 + tid] = fmaxf(v, 0.f);
    }
}

extern "C" void kernel_launch(void* const* d_in, const int* in_sizes, int n_in,
                              void* d_out, int out_size, void* d_ws, size_t ws_size,
                              hipStream_t stream) {
    const int*   text  = (const int*)d_in[0];
    const float* embed = (const float*)d_in[1];
    const float* w3    = (const float*)d_in[2];
    const float* b3    = (const float*)d_in[3];
    const float* w4    = (const float*)d_in[4];
    const float* b4    = (const float*)d_in[5];
    const float* w5    = (const float*)d_in[6];
    const float* b5    = (const float*)d_in[7];
    float* out = (float*)d_out;

    __bf16* x  = (__bf16*)d_ws;                 // 1024*132*512 bf16 = 138.4 MB
    __bf16* wq = x + XELEMS;                    // 1572864 bf16 = 3.1 MB

    (void)hipFuncSetAttribute((const void*)conv_gemm_kernel,
                              hipFuncAttributeMaxDynamicSharedMemorySize,
                              SLAB_BYTES);

    pack_x_kernel<<<1024 * XROWS / 4, 256, 0, stream>>>(text, embed, x);
    pack_w_kernel<<<768, 256, 0, stream>>>(w3, w4, w5, wq);
    conv_gemm_kernel<<<3072, 512, SLAB_BYTES, stream>>>(x, wq, b3, b4, b5, out);
}